// Round 5
// baseline (15971.857 us; speedup 1.0000x reference)
//
#include <hip/hip_runtime.h>

// Problem constants (match reference setup_inputs)
constexpr int NVn = 200000;   // var nodes, 9 feats in
constexpr int NCn = 100000;   // cstr nodes, 1 feat in
constexpr int NEn = 1000000;  // edges
constexpr int NBb = 32;       // graphs
#define EPSf 1e-5f

// ---------------- degree count ----------------
__global__ __launch_bounds__(256) void k_count_deg(const int* __restrict__ src, const int* __restrict__ dst,
                            int* __restrict__ degv, int* __restrict__ degc) {
    for (int e = blockIdx.x * blockDim.x + threadIdx.x; e < NEn; e += gridDim.x * blockDim.x) {
        atomicAdd(&degv[dst[e]], 1);
        atomicAdd(&degc[src[e]], 1);
    }
}

// ---------------- exclusive scan (3 kernels, 1024 elems/block) ----------------
__global__ __launch_bounds__(256) void k_scan_block(const int* __restrict__ deg, int n, int* __restrict__ bsum) {
    __shared__ int s[256];
    int base = blockIdx.x * 1024;
    int t = threadIdx.x;
    int v = 0;
#pragma unroll
    for (int j = 0; j < 4; j++) { int idx = base + t * 4 + j; if (idx < n) v += deg[idx]; }
    s[t] = v; __syncthreads();
    for (int o = 128; o > 0; o >>= 1) { if (t < o) s[t] += s[t + o]; __syncthreads(); }
    if (t == 0) bsum[blockIdx.x] = s[0];
}

__global__ __launch_bounds__(1024) void k_scan_tops(int* bsum, int nb) {
    __shared__ int s[1024];
    int t = threadIdx.x;
    int v = (t < nb) ? bsum[t] : 0;
    s[t] = v; __syncthreads();
    for (int o = 1; o < 1024; o <<= 1) {
        int x = (t >= o) ? s[t - o] : 0; __syncthreads();
        s[t] += x; __syncthreads();
    }
    if (t < nb) bsum[t] = s[t] - v;  // exclusive
}

__global__ __launch_bounds__(256) void k_scan_final(const int* __restrict__ deg, int n, const int* __restrict__ bsum,
                             int* __restrict__ off, int* __restrict__ cur) {
    __shared__ int s[256];
    int base = blockIdx.x * 1024, t = threadIdx.x;
    int d[4], loc[4], sum = 0;
#pragma unroll
    for (int j = 0; j < 4; j++) {
        int idx = base + t * 4 + j;
        d[j] = (idx < n) ? deg[idx] : 0;
        loc[j] = sum; sum += d[j];
    }
    s[t] = sum; __syncthreads();
    int v = sum;
    for (int o = 1; o < 256; o <<= 1) {
        int x = (t >= o) ? s[t - o] : 0; __syncthreads();
        s[t] += x; __syncthreads();
    }
    int texcl = s[t] - v + bsum[blockIdx.x];
#pragma unroll
    for (int j = 0; j < 4; j++) {
        int idx = base + t * 4 + j;
        if (idx < n) {
            int o2 = texcl + loc[j];
            off[idx] = o2; cur[idx] = o2;
            if (idx == n - 1) off[n] = o2 + d[j];
        }
    }
}

// ---------------- CSR fill (w = ew / deg) ----------------
__global__ __launch_bounds__(256) void k_fill(const int* __restrict__ key, const int* __restrict__ other,
                       const float* __restrict__ ew, const int* __restrict__ off,
                       int* __restrict__ cur, int* __restrict__ col, float* __restrict__ w) {
    for (int e = blockIdx.x * blockDim.x + threadIdx.x; e < NEn; e += gridDim.x * blockDim.x) {
        int d = key[e];
        int p = atomicAdd(&cur[d], 1);
        col[p] = other[e];
        float invd = 1.0f / (float)(off[d + 1] - off[d]);
        w[p] = ew[e] * invd;
    }
}

__global__ __launch_bounds__(256) void k_wsum(const int* __restrict__ off, const float* __restrict__ w,
                       float* __restrict__ ws, int n) {
    for (int i = blockIdx.x * blockDim.x + threadIdx.x; i < n; i += gridDim.x * blockDim.x) {
        int s = off[i], e = off[i + 1]; float t = 0.f;
        for (int j = s; j < e; j++) t += w[j];
        ws[i] = t;
    }
}

// ---------------- BN column stats ----------------
// acc layout: [0..63]=sum, [64..127]=sumsq (pre-zeroed)
__global__ __launch_bounds__(256) void k_stats64(const float* __restrict__ x, int n, float* __restrict__ acc) {
    int c = threadIdx.x & 63, r4 = threadIdx.x >> 6;
    float s = 0.f, q = 0.f;
    for (int i = blockIdx.x * 4 + r4; i < n; i += gridDim.x * 4) {
        float v = x[i * 64 + c]; s += v; q = fmaf(v, v, q);
    }
    __shared__ float ls[256];
    ls[threadIdx.x] = s; __syncthreads();
    if (r4 == 0) atomicAdd(&acc[c], ls[c] + ls[c + 64] + ls[c + 128] + ls[c + 192]);
    __syncthreads();
    ls[threadIdx.x] = q; __syncthreads();
    if (r4 == 0) atomicAdd(&acc[64 + c], ls[c] + ls[c + 64] + ls[c + 128] + ls[c + 192]);
}

template <int D>
__global__ __launch_bounds__(256) void k_stats_small(const float* __restrict__ x, int n, float* __restrict__ acc) {
    float s[D], q[D];
#pragma unroll
    for (int k = 0; k < D; k++) { s[k] = 0.f; q[k] = 0.f; }
    for (int i = blockIdx.x * blockDim.x + threadIdx.x; i < n; i += gridDim.x * blockDim.x) {
#pragma unroll
        for (int k = 0; k < D; k++) { float v = x[i * D + k]; s[k] += v; q[k] = fmaf(v, v, q[k]); }
    }
#pragma unroll
    for (int k = 0; k < D; k++) { atomicAdd(&acc[k], s[k]); atomicAdd(&acc[D + k], q[k]); }
}

// ---------------- fold BN into weights ----------------
// acc layout: sums at [0..D), sumsq at [D..2D)
__global__ __launch_bounds__(64) void k_fold(const float* __restrict__ Wrel, const float* __restrict__ brel,
                       const float* __restrict__ Wroot,
                       const float* __restrict__ gs, const float* __restrict__ bs,
                       const float* __restrict__ accs, float invNs, int DSv,
                       const float* __restrict__ gd, const float* __restrict__ bd,
                       const float* __restrict__ accd, float invNd, int DDv,
                       float* __restrict__ Wr_o, float* __restrict__ Wt_o,
                       float* __restrict__ b0_o, float* __restrict__ bw_o) {
    int h = threadIdx.x;  // 64 threads
    float bw = 0.f, b0 = brel[h];
    for (int k = 0; k < DSv; k++) {
        float m = accs[k] * invNs;
        float var = accs[DSv + k] * invNs - m * m;
        float a = gs[k] * rsqrtf(var + EPSf);
        float be = bs[k] - m * a;
        float wv = Wrel[k * 64 + h];
        Wr_o[k * 64 + h] = a * wv;
        bw = fmaf(be, wv, bw);
    }
    for (int k = 0; k < DDv; k++) {
        float m = accd[k] * invNd;
        float var = accd[DDv + k] * invNd - m * m;
        float a = gd[k] * rsqrtf(var + EPSf);
        float be = bd[k] - m * a;
        float wv = Wroot[k * 64 + h];
        Wt_o[k * 64 + h] = a * wv;
        b0 = fmaf(be, wv, b0);
    }
    b0_o[h] = b0; bw_o[h] = bw;
}

// ---------------- aggregation (gather form from CSR) ----------------
// wave per node; lane = feature (lane < DS active)
template <int DS>
__global__ __launch_bounds__(256) void k_agg(const float* __restrict__ xs, const int* __restrict__ off,
                      const int* __restrict__ col, const float* __restrict__ w,
                      float* __restrict__ agg, int n) {
    int lane = threadIdx.x & 63;
    int wid = (blockIdx.x * blockDim.x + threadIdx.x) >> 6;
    int nw = (gridDim.x * blockDim.x) >> 6;
    for (int i = wid; i < n; i += nw) {
        int s = off[i], e = off[i + 1];
        if (lane < DS) {
            float a0 = 0.f, a1 = 0.f;
            int j = s;
            for (; j + 1 < e; j += 2) {
                int c0 = col[j], c1 = col[j + 1];
                float w0 = w[j], w1 = w[j + 1];
                a0 = fmaf(w0, xs[c0 * DS + lane], a0);
                a1 = fmaf(w1, xs[c1 * DS + lane], a1);
            }
            if (j < e) a0 = fmaf(w[j], xs[col[j] * DS + lane], a0);
            agg[i * DS + lane] = a0 + a1;
        }
    }
}

// DS==1 specialization: thread per node
__global__ __launch_bounds__(256) void k_agg1(const float* __restrict__ xs, const int* __restrict__ off,
                       const int* __restrict__ col, const float* __restrict__ w,
                       float* __restrict__ agg, int n) {
    for (int i = blockIdx.x * blockDim.x + threadIdx.x; i < n; i += gridDim.x * blockDim.x) {
        int s = off[i], e = off[i + 1]; float a = 0.f;
        for (int j = s; j < e; j++) a = fmaf(w[j], xs[col[j]], a);
        agg[i] = a;
    }
}

// ---------------- layer-0 small-K GEMM: thread per (node, h) ----------------
template <int KS, int KD>
__global__ __launch_bounds__(256) void k_gemm0(const float* __restrict__ aggs, const float* __restrict__ xd,
                        const float* __restrict__ wsum,
                        const float* __restrict__ Wr, const float* __restrict__ Wt,
                        const float* __restrict__ b0, const float* __restrict__ bw,
                        float* __restrict__ out, int n) {
    int idx = blockIdx.x * blockDim.x + threadIdx.x;
    int i = idx >> 6, h = idx & 63;
    if (i >= n) return;
    float acc = b0[h] + wsum[i] * bw[h];
#pragma unroll
    for (int k = 0; k < KS; k++) acc = fmaf(aggs[i * KS + k], Wr[k * 64 + h], acc);
#pragma unroll
    for (int k = 0; k < KD; k++) acc = fmaf(xd[i * KD + k], Wt[k * 64 + h], acc);
    out[i * 64 + h] = fmaxf(acc, 0.0f);
}

// ---------------- main GEMM: out = relu(agg@Wr + xroot@Wt + b0 + wsum*bw) ----------------
// tile 128 rows x 64 cols, 256 threads, 4x8 per thread, K = 64(agg) + 64(root) in 4 panels of 32.
// Register budget (round-4 lesson): (256,2) empirically caps the allocator at 128 VGPRs,
// and the old 8x8 tile (~150 regs) spilled acc -> 3.5 GB scratch traffic per dispatch
// (FETCH_SIZE counter), VALUBusy 1.4%. This 4x8 tile with streamed bv needs
// acc32 + av16 + bv4..32 + addr ~= 80..110 regs -> fits with margin.
// NOTE: `agg` and `out` intentionally alias (in-place): each block reads only its own
// rows (all panel loads complete before the epilogue stores). No __restrict__ on them.
__global__ __launch_bounds__(256, 2) void k_gemm(const float* agg, const float* __restrict__ xroot,
                       const float* __restrict__ wsum,
                       const float* __restrict__ Wr, const float* __restrict__ Wt,
                       const float* __restrict__ b0, const float* __restrict__ bw,
                       float* out, int n) {
    __shared__ __align__(16) float sIn[128 * 36];
    __shared__ __align__(16) float sWT[64 * 36];
    int t = threadIdx.x;
    int tr = t >> 3, tc = t & 7;      // tr 0..31 (row base), tc 0..7 (col base)
    int base = blockIdx.x * 128;
    float acc[4][8];
#pragma unroll
    for (int a = 0; a < 4; a++)
#pragma unroll
        for (int b = 0; b < 8; b++) acc[a][b] = 0.f;

#pragma unroll
    for (int p = 0; p < 4; p++) {
        const float* src = (p < 2) ? agg : xroot;
        const float* W = (p < 2) ? Wr : Wt;
        int k0 = (p & 1) * 32;
        // stage input panel [128][32] -> sIn[128][36]: 1024 float4, 4 per thread
#pragma unroll
        for (int ii = 0; ii < 4; ii++) {
            int lin = t + 256 * ii;
            int r = lin >> 3, kq = lin & 7;
            int grow = base + r;
            float4 v = make_float4(0.f, 0.f, 0.f, 0.f);
            if (grow < n) v = *(const float4*)(src + (size_t)grow * 64 + k0 + kq * 4);
            *(float4*)(sIn + r * 36 + kq * 4) = v;
        }
        // stage weights transposed: sWT[c][k] = W[k0+k][c]  (2048 scalars, 8 per thread)
#pragma unroll
        for (int ii = 0; ii < 8; ii++) {
            int lin = t + 256 * ii;     // 2048 = 32k * 64c
            int k = lin >> 6, c = lin & 63;
            sWT[c * 36 + k] = W[(k0 + k) * 64 + c];
        }
        __syncthreads();
#pragma unroll
        for (int k4 = 0; k4 < 8; k4++) {
            float4 av[4];
#pragma unroll
            for (int rr = 0; rr < 4; rr++) av[rr] = *(const float4*)(sIn + (tr + 32 * rr) * 36 + k4 * 4);
#pragma unroll
            for (int cc = 0; cc < 8; cc++) {
                float4 bv = *(const float4*)(sWT + (tc + 8 * cc) * 36 + k4 * 4);
#pragma unroll
                for (int rr = 0; rr < 4; rr++) {
                    acc[rr][cc] = fmaf(av[rr].x, bv.x, acc[rr][cc]);
                    acc[rr][cc] = fmaf(av[rr].y, bv.y, acc[rr][cc]);
                    acc[rr][cc] = fmaf(av[rr].z, bv.z, acc[rr][cc]);
                    acc[rr][cc] = fmaf(av[rr].w, bv.w, acc[rr][cc]);
                }
            }
        }
        __syncthreads();
    }
    float b0c[8], bwc[8];
#pragma unroll
    for (int cc = 0; cc < 8; cc++) { int c = tc + 8 * cc; b0c[cc] = b0[c]; bwc[cc] = bw[c]; }
#pragma unroll
    for (int rr = 0; rr < 4; rr++) {
        int grow = base + tr + 32 * rr;
        if (grow < n) {
            float ws = wsum[grow];
#pragma unroll
            for (int cc = 0; cc < 8; cc++) {
                int c = tc + 8 * cc;
                float v = acc[rr][cc] + b0c[cc] + ws * bwc[cc];
                out[(size_t)grow * 64 + c] = fmaxf(v, 0.0f);
            }
        }
    }
}

// ---------------- pooling ----------------
// per-batch counts via in-wave run-length (batch sorted)
__global__ __launch_bounds__(256) void k_seg_count(const int* __restrict__ batch, int n, int* __restrict__ cnt) {
    int i = blockIdx.x * blockDim.x + threadIdx.x;
    if (i >= n) return;
    int lane = threadIdx.x & 63;
    int b = batch[i];
    int bprev = __shfl_up(b, 1);
    bool head = (lane == 0) || (b != bprev);
    unsigned long long hb = __ballot(head);
    if (head) {
        unsigned long long mask = (lane == 63) ? 0ULL : (hb >> (lane + 1));
        int wstart = i - lane;
        int nvalid = min(64, n - wstart);
        int end = (mask == 0ULL) ? nvalid : (lane + 1 + __ffsll((long long)mask) - 1);
        atomicAdd(&cnt[b], end - lane);
    }
}

// column-wise sums with local run accumulation (batch sorted -> few atomics)
__global__ __launch_bounds__(256) void k_pool_accum(const float* __restrict__ x, const int* __restrict__ batch,
                             int n, float* __restrict__ sums) {
    int c = threadIdx.x & 63, r4 = threadIdx.x >> 6;
    int start = blockIdx.x * 2048 + r4;
    int end = min(n, (int)(blockIdx.x * 2048 + 2048));
    float acc = 0.f; int cur = -1;
    for (int i = start; i < end; i += 4) {
        int b = batch[i];
        if (b != cur) {
            if (cur >= 0) atomicAdd(&sums[cur * 64 + c], acc);
            acc = 0.f; cur = b;
        }
        acc += x[(size_t)i * 64 + c];
    }
    if (cur >= 0) atomicAdd(&sums[cur * 64 + c], acc);
}

__global__ __launch_bounds__(256) void k_pool_div(const float* __restrict__ sv, const float* __restrict__ sc,
                           const int* __restrict__ cv, const int* __restrict__ cc2,
                           float* __restrict__ out) {
    int idx = blockIdx.x * blockDim.x + threadIdx.x;
    if (idx >= NBb * 128) return;
    int b = idx >> 7, j = idx & 127;
    float v;
    if (j < 64) v = sv[b * 64 + j] / fmaxf((float)cv[b], 1.0f);
    else        v = sc[b * 64 + (j - 64)] / fmaxf((float)cc2[b], 1.0f);
    out[idx] = v;
}

// ==================================================================
extern "C" void kernel_launch(void* const* d_in, const int* in_sizes, int n_in,
                              void* d_out, int out_size, void* d_ws, size_t ws_size,
                              hipStream_t stream) {
    (void)in_sizes; (void)n_in; (void)out_size; (void)ws_size;
    const float* var_feats = (const float*)d_in[0];
    const float* cstr_feats = (const float*)d_in[1];
    const float* edge_attr = (const float*)d_in[2];
    const float* Wrel_v0 = (const float*)d_in[3];
    const float* brel_v0 = (const float*)d_in[4];
    const float* Wroot_v0 = (const float*)d_in[5];
    const float* Wrel_c0 = (const float*)d_in[6];
    const float* brel_c0 = (const float*)d_in[7];
    const float* Wroot_c0 = (const float*)d_in[8];
    const float* g_v0 = (const float*)d_in[9];
    const float* b_v0 = (const float*)d_in[10];
    const float* g_c0 = (const float*)d_in[11];
    const float* b_c0 = (const float*)d_in[12];
    const float* Wrel_v = (const float*)d_in[13];
    const float* brel_v = (const float*)d_in[14];
    const float* Wroot_v = (const float*)d_in[15];
    const float* Wrel_c = (const float*)d_in[16];
    const float* brel_c = (const float*)d_in[17];
    const float* Wroot_c = (const float*)d_in[18];
    const float* g_v = (const float*)d_in[19];
    const float* b_v = (const float*)d_in[20];
    const float* g_c = (const float*)d_in[21];
    const float* b_c = (const float*)d_in[22];
    const int* edge_index = (const int*)d_in[23];
    const int* var_batch = (const int*)d_in[24];
    const int* cstr_batch = (const int*)d_in[25];
    const int* src_c = edge_index;
    const int* dst_v = edge_index + NEn;
    float* out = (float*)d_out;

    // ---- workspace carve-out ----
    char* ws = (char*)d_ws;
    size_t off_b = 0;
    auto alloc = [&](size_t bytes) -> char* {
        char* p = ws + off_b;
        off_b = (off_b + bytes + 255) & ~(size_t)255;
        return p;
    };
    float* V0 = (float*)alloc((size_t)NVn * 64 * 4);
    float* V1 = (float*)alloc((size_t)NVn * 64 * 4);
    float* C0 = (float*)alloc((size_t)NCn * 64 * 4);
    float* C1 = (float*)alloc((size_t)NCn * 64 * 4);
    int* off_v = (int*)alloc((size_t)(NVn + 1) * 4);
    int* cur_v = (int*)alloc((size_t)NVn * 4);
    int* col_v = (int*)alloc((size_t)NEn * 4);
    float* w_v = (float*)alloc((size_t)NEn * 4);
    int* off_c = (int*)alloc((size_t)(NCn + 1) * 4);
    int* cur_c = (int*)alloc((size_t)NCn * 4);
    int* col_c = (int*)alloc((size_t)NEn * 4);
    float* w_c = (float*)alloc((size_t)NEn * 4);
    float* wsum_v = (float*)alloc((size_t)NVn * 4);
    float* wsum_c = (float*)alloc((size_t)NCn * 4);
    int* degzone = (int*)alloc((size_t)(NVn + NCn) * 4);
    int* degv = degzone;
    int* degc = degzone + NVn;
    int* bsum = (int*)alloc(1024 * 4);
    // zero-init zone (one memset): stats accums + pool sums + counts
    float* zzone = (float*)alloc(4992 * 4);
    float* accL0v = zzone;            // 32 (18 used)
    float* accL0c = zzone + 32;       // 8 (2 used)
    float* accLv[3], *accLc[3];
    for (int l = 0; l < 3; l++) { accLv[l] = zzone + 64 + l * 256; accLc[l] = zzone + 64 + l * 256 + 128; }
    float* pool_sv = zzone + 832;     // 2048
    float* pool_sc = zzone + 2880;    // 2048
    int* cnt_v = (int*)(zzone + 4928);  // 32
    int* cnt_c = (int*)(zzone + 4960);  // 32
    // folded weights (reused each layer)
    float* Wr_v = (float*)alloc(4096 * 4);
    float* Wt_v = (float*)alloc(4096 * 4);
    float* b0_v = (float*)alloc(64 * 4);
    float* bw_v = (float*)alloc(64 * 4);
    float* Wr_c = (float*)alloc(4096 * 4);
    float* Wt_c = (float*)alloc(4096 * 4);
    float* b0_c = (float*)alloc(64 * 4);
    float* bw_c = (float*)alloc(64 * 4);

    const float invNV = 1.0f / (float)NVn;
    const float invNC = 1.0f / (float)NCn;

    // ---- init ----
    hipMemsetAsync(degzone, 0, (size_t)(NVn + NCn) * 4, stream);
    hipMemsetAsync(zzone, 0, 4992 * 4, stream);

    // ---- build CSR both directions ----
    k_count_deg<<<2048, 256, 0, stream>>>(src_c, dst_v, degv, degc);
    int nbv = (NVn + 1023) / 1024;  // 196
    int nbc = (NCn + 1023) / 1024;  // 98
    k_scan_block<<<nbv, 256, 0, stream>>>(degv, NVn, bsum);
    k_scan_tops<<<1, 1024, 0, stream>>>(bsum, nbv);
    k_scan_final<<<nbv, 256, 0, stream>>>(degv, NVn, bsum, off_v, cur_v);
    k_scan_block<<<nbc, 256, 0, stream>>>(degc, NCn, bsum);
    k_scan_tops<<<1, 1024, 0, stream>>>(bsum, nbc);
    k_scan_final<<<nbc, 256, 0, stream>>>(degc, NCn, bsum, off_c, cur_c);
    k_fill<<<2048, 256, 0, stream>>>(dst_v, src_c, edge_attr, off_v, cur_v, col_v, w_v);
    k_fill<<<2048, 256, 0, stream>>>(src_c, dst_v, edge_attr, off_c, cur_c, col_c, w_c);
    k_wsum<<<784, 256, 0, stream>>>(off_v, w_v, wsum_v, NVn);
    k_wsum<<<392, 256, 0, stream>>>(off_c, w_c, wsum_c, NCn);

    // ---- layer 0 (var: 9 feats, cstr: 1 feat) ----
    k_stats_small<9><<<128, 256, 0, stream>>>(var_feats, NVn, accL0v);
    k_stats_small<1><<<128, 256, 0, stream>>>(cstr_feats, NCn, accL0c);
    // v update: src=cstr (DS=1), dst=var (DD=9)
    k_fold<<<1, 64, 0, stream>>>(Wrel_v0, brel_v0, Wroot_v0,
                                 g_c0, b_c0, accL0c, invNC, 1,
                                 g_v0, b_v0, accL0v, invNV, 9,
                                 Wr_v, Wt_v, b0_v, bw_v);
    // c update: src=var (DS=9), dst=cstr (DD=1)
    k_fold<<<1, 64, 0, stream>>>(Wrel_c0, brel_c0, Wroot_c0,
                                 g_v0, b_v0, accL0v, invNV, 9,
                                 g_c0, b_c0, accL0c, invNC, 1,
                                 Wr_c, Wt_c, b0_c, bw_c);
    k_agg1<<<784, 256, 0, stream>>>(cstr_feats, off_v, col_v, w_v, V0, NVn);       // [NV,1]
    k_agg<9><<<2048, 256, 0, stream>>>(var_feats, off_c, col_c, w_c, C0, NCn);     // [NC,9]
    k_gemm0<1, 9><<<(NVn * 64 + 255) / 256, 256, 0, stream>>>(V0, var_feats, wsum_v,
                                                              Wr_v, Wt_v, b0_v, bw_v, V1, NVn);
    k_gemm0<9, 1><<<(NCn * 64 + 255) / 256, 256, 0, stream>>>(C0, cstr_feats, wsum_c,
                                                              Wr_c, Wt_c, b0_c, bw_c, C1, NCn);

    // ---- layers 1..3 ----
    float* xv = V1; float* xc = C1; float* av = V0; float* ac = C0;
    for (int l = 0; l < 3; l++) {
        const float* Wrv = Wrel_v + (size_t)l * 4096;
        const float* brv = brel_v + (size_t)l * 64;
        const float* Wtv = Wroot_v + (size_t)l * 4096;
        const float* Wrc = Wrel_c + (size_t)l * 4096;
        const float* brc = brel_c + (size_t)l * 64;
        const float* Wtc = Wroot_c + (size_t)l * 4096;
        const float* gvl = g_v + (size_t)l * 64; const float* bvl = b_v + (size_t)l * 64;
        const float* gcl = g_c + (size_t)l * 64; const float* bcl = b_c + (size_t)l * 64;

        k_stats64<<<1024, 256, 0, stream>>>(xv, NVn, accLv[l]);
        k_stats64<<<1024, 256, 0, stream>>>(xc, NCn, accLc[l]);
        k_fold<<<1, 64, 0, stream>>>(Wrv, brv, Wtv,
                                     gcl, bcl, accLc[l], invNC, 64,
                                     gvl, bvl, accLv[l], invNV, 64,
                                     Wr_v, Wt_v, b0_v, bw_v);
        k_fold<<<1, 64, 0, stream>>>(Wrc, brc, Wtc,
                                     gvl, bvl, accLv[l], invNV, 64,
                                     gcl, bcl, accLc[l], invNC, 64,
                                     Wr_c, Wt_c, b0_c, bw_c);
        k_agg<64><<<2048, 256, 0, stream>>>(xc, off_v, col_v, w_v, av, NVn);
        k_agg<64><<<2048, 256, 0, stream>>>(xv, off_c, col_c, w_c, ac, NCn);
        k_gemm<<<(NVn + 127) / 128, 256, 0, stream>>>(av, xv, wsum_v, Wr_v, Wt_v, b0_v, bw_v, av, NVn);
        k_gemm<<<(NCn + 127) / 128, 256, 0, stream>>>(ac, xc, wsum_c, Wr_c, Wt_c, b0_c, bw_c, ac, NCn);
        // swap
        float* tv = xv; xv = av; av = tv;
        float* tcp = xc; xc = ac; ac = tcp;
    }

    // ---- pooling ----
    k_seg_count<<<(NVn + 255) / 256, 256, 0, stream>>>(var_batch, NVn, cnt_v);
    k_seg_count<<<(NCn + 255) / 256, 256, 0, stream>>>(cstr_batch, NCn, cnt_c);
    k_pool_accum<<<(NVn + 2047) / 2048, 256, 0, stream>>>(xv, var_batch, NVn, pool_sv);
    k_pool_accum<<<(NCn + 2047) / 2048, 256, 0, stream>>>(xc, cstr_batch, NCn, pool_sc);
    k_pool_div<<<(NBb * 128 + 255) / 256, 256, 0, stream>>>(pool_sv, pool_sc, cnt_v, cnt_c, out);
}

// Round 7
// 1858.934 us; speedup vs baseline: 8.5919x; 8.5919x over previous
//
#include <hip/hip_runtime.h>

// Problem constants (match reference setup_inputs)
constexpr int NVn = 200000;   // var nodes, 9 feats in
constexpr int NCn = 100000;   // cstr nodes, 1 feat in
constexpr int NEn = 1000000;  // edges
constexpr int NBb = 32;       // graphs
#define EPSf 1e-5f

typedef __attribute__((ext_vector_type(8))) short s8v;   // 8 bf16 (4 VGPRs)
typedef __attribute__((ext_vector_type(4))) float f4v;   // 4 f32 acc

// f32 -> bf16 bits, round-to-nearest-even
static __device__ __forceinline__ unsigned short f2b(float f) {
    union { float f; unsigned u; } x; x.f = f;
    return (unsigned short)((x.u + 0x7FFFu + ((x.u >> 16) & 1u)) >> 16);
}

// load 8 consecutive f32, convert to bf16x8 fragment
static __device__ __forceinline__ s8v cvt8(const float* p) {
    float4 a = *(const float4*)p;
    float4 b = *(const float4*)(p + 4);
    s8v r;
    r[0] = (short)f2b(a.x); r[1] = (short)f2b(a.y); r[2] = (short)f2b(a.z); r[3] = (short)f2b(a.w);
    r[4] = (short)f2b(b.x); r[5] = (short)f2b(b.y); r[6] = (short)f2b(b.z); r[7] = (short)f2b(b.w);
    return r;
}

// store folded weight W[kg][h] (kg in 0..127, h in 0..63) into MFMA B-fragment order:
// fragment (ks=kg>>5, ct=h>>4), lane = ((kg>>3)&3)<<4 | (h&15), elem j = kg&7
static __device__ __forceinline__ void frag_store(unsigned short* B, int kg, int h, float w) {
    int ks = kg >> 5, g = (kg >> 3) & 3, j = kg & 7, ct = h >> 4;
    int lane = (g << 4) | (h & 15);
    B[((((ks << 2) | ct) << 6) | lane) * 8 + j] = f2b(w);
}

// ---------------- degree count ----------------
__global__ __launch_bounds__(256) void k_count_deg(const int* __restrict__ src, const int* __restrict__ dst,
                            int* __restrict__ degv, int* __restrict__ degc) {
    for (int e = blockIdx.x * blockDim.x + threadIdx.x; e < NEn; e += gridDim.x * blockDim.x) {
        atomicAdd(&degv[dst[e]], 1);
        atomicAdd(&degc[src[e]], 1);
    }
}

// ---------------- exclusive scan (3 kernels, 1024 elems/block) ----------------
__global__ __launch_bounds__(256) void k_scan_block(const int* __restrict__ deg, int n, int* __restrict__ bsum) {
    __shared__ int s[256];
    int base = blockIdx.x * 1024;
    int t = threadIdx.x;
    int v = 0;
#pragma unroll
    for (int j = 0; j < 4; j++) { int idx = base + t * 4 + j; if (idx < n) v += deg[idx]; }
    s[t] = v; __syncthreads();
    for (int o = 128; o > 0; o >>= 1) { if (t < o) s[t] += s[t + o]; __syncthreads(); }
    if (t == 0) bsum[blockIdx.x] = s[0];
}

__global__ __launch_bounds__(1024) void k_scan_tops(int* bsum, int nb) {
    __shared__ int s[1024];
    int t = threadIdx.x;
    int v = (t < nb) ? bsum[t] : 0;
    s[t] = v; __syncthreads();
    for (int o = 1; o < 1024; o <<= 1) {
        int x = (t >= o) ? s[t - o] : 0; __syncthreads();
        s[t] += x; __syncthreads();
    }
    if (t < nb) bsum[t] = s[t] - v;  // exclusive
}

__global__ __launch_bounds__(256) void k_scan_final(const int* __restrict__ deg, int n, const int* __restrict__ bsum,
                             int* __restrict__ off, int* __restrict__ cur) {
    __shared__ int s[256];
    int base = blockIdx.x * 1024, t = threadIdx.x;
    int d[4], loc[4], sum = 0;
#pragma unroll
    for (int j = 0; j < 4; j++) {
        int idx = base + t * 4 + j;
        d[j] = (idx < n) ? deg[idx] : 0;
        loc[j] = sum; sum += d[j];
    }
    s[t] = sum; __syncthreads();
    int v = sum;
    for (int o = 1; o < 256; o <<= 1) {
        int x = (t >= o) ? s[t - o] : 0; __syncthreads();
        s[t] += x; __syncthreads();
    }
    int texcl = s[t] - v + bsum[blockIdx.x];
#pragma unroll
    for (int j = 0; j < 4; j++) {
        int idx = base + t * 4 + j;
        if (idx < n) {
            int o2 = texcl + loc[j];
            off[idx] = o2; cur[idx] = o2;
            if (idx == n - 1) off[n] = o2 + d[j];
        }
    }
}

// ---------------- CSR fill (w = ew / deg) ----------------
__global__ __launch_bounds__(256) void k_fill(const int* __restrict__ key, const int* __restrict__ other,
                       const float* __restrict__ ew, const int* __restrict__ off,
                       int* __restrict__ cur, int* __restrict__ col, float* __restrict__ w) {
    for (int e = blockIdx.x * blockDim.x + threadIdx.x; e < NEn; e += gridDim.x * blockDim.x) {
        int d = key[e];
        int p = atomicAdd(&cur[d], 1);
        col[p] = other[e];
        float invd = 1.0f / (float)(off[d + 1] - off[d]);
        w[p] = ew[e] * invd;
    }
}

__global__ __launch_bounds__(256) void k_wsum(const int* __restrict__ off, const float* __restrict__ w,
                       float* __restrict__ ws, int n) {
    for (int i = blockIdx.x * blockDim.x + threadIdx.x; i < n; i += gridDim.x * blockDim.x) {
        int s = off[i], e = off[i + 1]; float t = 0.f;
        for (int j = s; j < e; j++) t += w[j];
        ws[i] = t;
    }
}

// ---------------- BN column stats ----------------
__global__ __launch_bounds__(256) void k_stats64(const float* __restrict__ x, int n, float* __restrict__ acc) {
    int c = threadIdx.x & 63, r4 = threadIdx.x >> 6;
    float s = 0.f, q = 0.f;
    for (int i = blockIdx.x * 4 + r4; i < n; i += gridDim.x * 4) {
        float v = x[i * 64 + c]; s += v; q = fmaf(v, v, q);
    }
    __shared__ float ls[256];
    ls[threadIdx.x] = s; __syncthreads();
    if (r4 == 0) atomicAdd(&acc[c], ls[c] + ls[c + 64] + ls[c + 128] + ls[c + 192]);
    __syncthreads();
    ls[threadIdx.x] = q; __syncthreads();
    if (r4 == 0) atomicAdd(&acc[64 + c], ls[c] + ls[c + 64] + ls[c + 128] + ls[c + 192]);
}

template <int D>
__global__ __launch_bounds__(256) void k_stats_small(const float* __restrict__ x, int n, float* __restrict__ acc) {
    float s[D], q[D];
#pragma unroll
    for (int k = 0; k < D; k++) { s[k] = 0.f; q[k] = 0.f; }
    for (int i = blockIdx.x * blockDim.x + threadIdx.x; i < n; i += gridDim.x * blockDim.x) {
#pragma unroll
        for (int k = 0; k < D; k++) { float v = x[i * D + k]; s[k] += v; q[k] = fmaf(v, v, q[k]); }
    }
#pragma unroll
    for (int k = 0; k < D; k++) { atomicAdd(&acc[k], s[k]); atomicAdd(&acc[D + k], q[k]); }
}

// ---------------- fold BN into weights (+ optional bf16 MFMA fragment output) ----------------
__global__ __launch_bounds__(64) void k_fold(const float* __restrict__ Wrel, const float* __restrict__ brel,
                       const float* __restrict__ Wroot,
                       const float* __restrict__ gs, const float* __restrict__ bs,
                       const float* __restrict__ accs, float invNs, int DSv,
                       const float* __restrict__ gd, const float* __restrict__ bd,
                       const float* __restrict__ accd, float invNd, int DDv,
                       float* __restrict__ Wr_o, float* __restrict__ Wt_o,
                       float* __restrict__ b0_o, float* __restrict__ bw_o,
                       unsigned short* __restrict__ Bfrag) {
    int h = threadIdx.x;  // 64 threads
    float bw = 0.f, b0 = brel[h];
    for (int k = 0; k < DSv; k++) {
        float m = accs[k] * invNs;
        float var = accs[DSv + k] * invNs - m * m;
        float a = gs[k] * rsqrtf(var + EPSf);
        float be = bs[k] - m * a;
        float wv = Wrel[k * 64 + h];
        float wf = a * wv;
        Wr_o[k * 64 + h] = wf;
        bw = fmaf(be, wv, bw);
        if (Bfrag) frag_store(Bfrag, k, h, wf);
    }
    for (int k = 0; k < DDv; k++) {
        float m = accd[k] * invNd;
        float var = accd[DDv + k] * invNd - m * m;
        float a = gd[k] * rsqrtf(var + EPSf);
        float be = bd[k] - m * a;
        float wv = Wroot[k * 64 + h];
        float wf = a * wv;
        Wt_o[k * 64 + h] = wf;
        b0 = fmaf(be, wv, b0);
        if (Bfrag) frag_store(Bfrag, 64 + k, h, wf);
    }
    b0_o[h] = b0; bw_o[h] = bw;
}

// ---------------- aggregation (gather form from CSR) ----------------
template <int DS>
__global__ __launch_bounds__(256) void k_agg(const float* __restrict__ xs, const int* __restrict__ off,
                      const int* __restrict__ col, const float* __restrict__ w,
                      float* __restrict__ agg, int n) {
    int lane = threadIdx.x & 63;
    int wid = (blockIdx.x * blockDim.x + threadIdx.x) >> 6;
    int nw = (gridDim.x * blockDim.x) >> 6;
    for (int i = wid; i < n; i += nw) {
        int s = off[i], e = off[i + 1];
        if (lane < DS) {
            float a0 = 0.f, a1 = 0.f;
            int j = s;
            for (; j + 1 < e; j += 2) {
                int c0 = col[j], c1 = col[j + 1];
                float w0 = w[j], w1 = w[j + 1];
                a0 = fmaf(w0, xs[c0 * DS + lane], a0);
                a1 = fmaf(w1, xs[c1 * DS + lane], a1);
            }
            if (j < e) a0 = fmaf(w[j], xs[col[j] * DS + lane], a0);
            agg[i * DS + lane] = a0 + a1;
        }
    }
}

// DS==1 specialization: thread per node
__global__ __launch_bounds__(256) void k_agg1(const float* __restrict__ xs, const int* __restrict__ off,
                       const int* __restrict__ col, const float* __restrict__ w,
                       float* __restrict__ agg, int n) {
    for (int i = blockIdx.x * blockDim.x + threadIdx.x; i < n; i += gridDim.x * blockDim.x) {
        int s = off[i], e = off[i + 1]; float a = 0.f;
        for (int j = s; j < e; j++) a = fmaf(w[j], xs[col[j]], a);
        agg[i] = a;
    }
}

// ---------------- layer-0 small-K GEMM: thread per (node, h) ----------------
template <int KS, int KD>
__global__ __launch_bounds__(256) void k_gemm0(const float* __restrict__ aggs, const float* __restrict__ xd,
                        const float* __restrict__ wsum,
                        const float* __restrict__ Wr, const float* __restrict__ Wt,
                        const float* __restrict__ b0, const float* __restrict__ bw,
                        float* __restrict__ out, int n) {
    int idx = blockIdx.x * blockDim.x + threadIdx.x;
    int i = idx >> 6, h = idx & 63;
    if (i >= n) return;
    float acc = b0[h] + wsum[i] * bw[h];
#pragma unroll
    for (int k = 0; k < KS; k++) acc = fmaf(aggs[i * KS + k], Wr[k * 64 + h], acc);
#pragma unroll
    for (int k = 0; k < KD; k++) acc = fmaf(xd[i * KD + k], Wt[k * 64 + h], acc);
    out[i * 64 + h] = fmaxf(acc, 0.0f);
}

// ---------------- main GEMM via MFMA bf16 ----------------
// out[n][64] = relu([agg|x][n][128] @ Bfrag[128][64] + b0 + wsum*bw)
// Block = 256 thr = 4 waves; wave w owns rows [blk*64 + 16w, +16), all 64 cols.
// Per wave: 4 k-steps x 4 col-tiles = 16 x mfma_f32_16x16x32_bf16, acc = 4x f32x4 (AGPR).
// A-fragments loaded straight from global f32 (coalesced 128B segs) + RNE cvt to bf16.
// B pre-formatted by k_fold in fragment order -> lane l loads 16B coalesced, L2-hot.
// No LDS, no __syncthreads, no per-thread arrays -> cannot spill (rounds 3-5 lesson:
// the f32 VALU tile's acc array went to scratch at any tile size; 3.5-6 GB FETCH).
// agg and out alias in-place: each wave reads/writes only its own 16 rows.
__global__ __launch_bounds__(256, 4) void k_gemm(const float* agg, const float* __restrict__ xroot,
                       const float* __restrict__ wsum, const unsigned short* __restrict__ Bfrag,
                       const float* __restrict__ b0, const float* __restrict__ bwv,
                       float* out, int n) {
    int t = threadIdx.x;
    int wv = t >> 6, l = t & 63;
    int lrow = l & 15, lkg = l >> 4;
    int base = blockIdx.x * 64 + wv * 16;
    int arow = base + lrow;
    if (arow >= n) arow = 0;                 // safe redirect for tail block
    const float* ap = agg + (size_t)arow * 64 + lkg * 8;
    const float* xp = xroot + (size_t)arow * 64 + lkg * 8;
    const unsigned short* Bl = Bfrag + l * 8;
    f4v acc0 = {0.f, 0.f, 0.f, 0.f};
    f4v acc1 = acc0, acc2 = acc0, acc3 = acc0;
#define KSTEP(ks, P)                                                        \
    {                                                                       \
        s8v a = cvt8(P);                                                    \
        s8v f0 = *(const s8v*)(Bl + ((ks) * 4 + 0) * 512);                  \
        s8v f1 = *(const s8v*)(Bl + ((ks) * 4 + 1) * 512);                  \
        s8v f2 = *(const s8v*)(Bl + ((ks) * 4 + 2) * 512);                  \
        s8v f3 = *(const s8v*)(Bl + ((ks) * 4 + 3) * 512);                  \
        acc0 = __builtin_amdgcn_mfma_f32_16x16x32_bf16(a, f0, acc0, 0, 0, 0); \
        acc1 = __builtin_amdgcn_mfma_f32_16x16x32_bf16(a, f1, acc1, 0, 0, 0); \
        acc2 = __builtin_amdgcn_mfma_f32_16x16x32_bf16(a, f2, acc2, 0, 0, 0); \
        acc3 = __builtin_amdgcn_mfma_f32_16x16x32_bf16(a, f3, acc3, 0, 0, 0); \
    }
    KSTEP(0, ap)
    KSTEP(1, ap + 32)
    KSTEP(2, xp)
    KSTEP(3, xp + 32)
#undef KSTEP
    // epilogue: C/D layout col = l&15 (+16*ct), row = 4*(l>>4) + reg
    int orow = base + lkg * 4;
    float ws0 = (orow + 0 < n) ? wsum[orow + 0] : 0.f;
    float ws1 = (orow + 1 < n) ? wsum[orow + 1] : 0.f;
    float ws2 = (orow + 2 < n) ? wsum[orow + 2] : 0.f;
    float ws3 = (orow + 3 < n) ? wsum[orow + 3] : 0.f;
#define EPI(ACC, ct)                                                                        \
    {                                                                                       \
        int c = (ct) * 16 + lrow;                                                           \
        float bb = b0[c], wb = bwv[c];                                                      \
        if (orow + 0 < n) out[(size_t)(orow + 0) * 64 + c] = fmaxf(ACC[0] + bb + ws0 * wb, 0.f); \
        if (orow + 1 < n) out[(size_t)(orow + 1) * 64 + c] = fmaxf(ACC[1] + bb + ws1 * wb, 0.f); \
        if (orow + 2 < n) out[(size_t)(orow + 2) * 64 + c] = fmaxf(ACC[2] + bb + ws2 * wb, 0.f); \
        if (orow + 3 < n) out[(size_t)(orow + 3) * 64 + c] = fmaxf(ACC[3] + bb + ws3 * wb, 0.f); \
    }
    EPI(acc0, 0)
    EPI(acc1, 1)
    EPI(acc2, 2)
    EPI(acc3, 3)
#undef EPI
}

// ---------------- pooling ----------------
__global__ __launch_bounds__(256) void k_seg_count(const int* __restrict__ batch, int n, int* __restrict__ cnt) {
    int i = blockIdx.x * blockDim.x + threadIdx.x;
    if (i >= n) return;
    int lane = threadIdx.x & 63;
    int b = batch[i];
    int bprev = __shfl_up(b, 1);
    bool head = (lane == 0) || (b != bprev);
    unsigned long long hb = __ballot(head);
    if (head) {
        unsigned long long mask = (lane == 63) ? 0ULL : (hb >> (lane + 1));
        int wstart = i - lane;
        int nvalid = min(64, n - wstart);
        int end = (mask == 0ULL) ? nvalid : (lane + 1 + __ffsll((long long)mask) - 1);
        atomicAdd(&cnt[b], end - lane);
    }
}

__global__ __launch_bounds__(256) void k_pool_accum(const float* __restrict__ x, const int* __restrict__ batch,
                             int n, float* __restrict__ sums) {
    int c = threadIdx.x & 63, r4 = threadIdx.x >> 6;
    int start = blockIdx.x * 2048 + r4;
    int end = min(n, (int)(blockIdx.x * 2048 + 2048));
    float acc = 0.f; int cur = -1;
    for (int i = start; i < end; i += 4) {
        int b = batch[i];
        if (b != cur) {
            if (cur >= 0) atomicAdd(&sums[cur * 64 + c], acc);
            acc = 0.f; cur = b;
        }
        acc += x[(size_t)i * 64 + c];
    }
    if (cur >= 0) atomicAdd(&sums[cur * 64 + c], acc);
}

__global__ __launch_bounds__(256) void k_pool_div(const float* __restrict__ sv, const float* __restrict__ sc,
                           const int* __restrict__ cv, const int* __restrict__ cc2,
                           float* __restrict__ out) {
    int idx = blockIdx.x * blockDim.x + threadIdx.x;
    if (idx >= NBb * 128) return;
    int b = idx >> 7, j = idx & 127;
    float v;
    if (j < 64) v = sv[b * 64 + j] / fmaxf((float)cv[b], 1.0f);
    else        v = sc[b * 64 + (j - 64)] / fmaxf((float)cc2[b], 1.0f);
    out[idx] = v;
}

// ==================================================================
extern "C" void kernel_launch(void* const* d_in, const int* in_sizes, int n_in,
                              void* d_out, int out_size, void* d_ws, size_t ws_size,
                              hipStream_t stream) {
    (void)in_sizes; (void)n_in; (void)out_size; (void)ws_size;
    const float* var_feats = (const float*)d_in[0];
    const float* cstr_feats = (const float*)d_in[1];
    const float* edge_attr = (const float*)d_in[2];
    const float* Wrel_v0 = (const float*)d_in[3];
    const float* brel_v0 = (const float*)d_in[4];
    const float* Wroot_v0 = (const float*)d_in[5];
    const float* Wrel_c0 = (const float*)d_in[6];
    const float* brel_c0 = (const float*)d_in[7];
    const float* Wroot_c0 = (const float*)d_in[8];
    const float* g_v0 = (const float*)d_in[9];
    const float* b_v0 = (const float*)d_in[10];
    const float* g_c0 = (const float*)d_in[11];
    const float* b_c0 = (const float*)d_in[12];
    const float* Wrel_v = (const float*)d_in[13];
    const float* brel_v = (const float*)d_in[14];
    const float* Wroot_v = (const float*)d_in[15];
    const float* Wrel_c = (const float*)d_in[16];
    const float* brel_c = (const float*)d_in[17];
    const float* Wroot_c = (const float*)d_in[18];
    const float* g_v = (const float*)d_in[19];
    const float* b_v = (const float*)d_in[20];
    const float* g_c = (const float*)d_in[21];
    const float* b_c = (const float*)d_in[22];
    const int* edge_index = (const int*)d_in[23];
    const int* var_batch = (const int*)d_in[24];
    const int* cstr_batch = (const int*)d_in[25];
    const int* src_c = edge_index;
    const int* dst_v = edge_index + NEn;
    float* out = (float*)d_out;

    // ---- workspace carve-out ----
    char* ws = (char*)d_ws;
    size_t off_b = 0;
    auto alloc = [&](size_t bytes) -> char* {
        char* p = ws + off_b;
        off_b = (off_b + bytes + 255) & ~(size_t)255;
        return p;
    };
    float* V0 = (float*)alloc((size_t)NVn * 64 * 4);
    float* V1 = (float*)alloc((size_t)NVn * 64 * 4);
    float* C0 = (float*)alloc((size_t)NCn * 64 * 4);
    float* C1 = (float*)alloc((size_t)NCn * 64 * 4);
    int* off_v = (int*)alloc((size_t)(NVn + 1) * 4);
    int* cur_v = (int*)alloc((size_t)NVn * 4);
    int* col_v = (int*)alloc((size_t)NEn * 4);
    float* w_v = (float*)alloc((size_t)NEn * 4);
    int* off_c = (int*)alloc((size_t)(NCn + 1) * 4);
    int* cur_c = (int*)alloc((size_t)NCn * 4);
    int* col_c = (int*)alloc((size_t)NEn * 4);
    float* w_c = (float*)alloc((size_t)NEn * 4);
    float* wsum_v = (float*)alloc((size_t)NVn * 4);
    float* wsum_c = (float*)alloc((size_t)NCn * 4);
    int* degzone = (int*)alloc((size_t)(NVn + NCn) * 4);
    int* degv = degzone;
    int* degc = degzone + NVn;
    int* bsum = (int*)alloc(1024 * 4);
    // zero-init zone (one memset): stats accums + pool sums + counts
    float* zzone = (float*)alloc(4992 * 4);
    float* accL0v = zzone;            // 32 (18 used)
    float* accL0c = zzone + 32;       // 8 (2 used)
    float* accLv[3], *accLc[3];
    for (int l = 0; l < 3; l++) { accLv[l] = zzone + 64 + l * 256; accLc[l] = zzone + 64 + l * 256 + 128; }
    float* pool_sv = zzone + 832;     // 2048
    float* pool_sc = zzone + 2880;    // 2048
    int* cnt_v = (int*)(zzone + 4928);  // 32
    int* cnt_c = (int*)(zzone + 4960);  // 32
    // folded weights
    float* Wr_v = (float*)alloc(4096 * 4);
    float* Wt_v = (float*)alloc(4096 * 4);
    float* b0_v = (float*)alloc(64 * 4);
    float* bw_v = (float*)alloc(64 * 4);
    float* Wr_c = (float*)alloc(4096 * 4);
    float* Wt_c = (float*)alloc(4096 * 4);
    float* b0_c = (float*)alloc(64 * 4);
    float* bw_c = (float*)alloc(64 * 4);
    // bf16 MFMA B-fragment buffers: [ks4][ct4][lane64][8 bf16]
    unsigned short* Bf_v = (unsigned short*)alloc(8192 * 2);
    unsigned short* Bf_c = (unsigned short*)alloc(8192 * 2);

    const float invNV = 1.0f / (float)NVn;
    const float invNC = 1.0f / (float)NCn;

    // ---- init ----
    hipMemsetAsync(degzone, 0, (size_t)(NVn + NCn) * 4, stream);
    hipMemsetAsync(zzone, 0, 4992 * 4, stream);

    // ---- build CSR both directions ----
    k_count_deg<<<2048, 256, 0, stream>>>(src_c, dst_v, degv, degc);
    int nbv = (NVn + 1023) / 1024;  // 196
    int nbc = (NCn + 1023) / 1024;  // 98
    k_scan_block<<<nbv, 256, 0, stream>>>(degv, NVn, bsum);
    k_scan_tops<<<1, 1024, 0, stream>>>(bsum, nbv);
    k_scan_final<<<nbv, 256, 0, stream>>>(degv, NVn, bsum, off_v, cur_v);
    k_scan_block<<<nbc, 256, 0, stream>>>(degc, NCn, bsum);
    k_scan_tops<<<1, 1024, 0, stream>>>(bsum, nbc);
    k_scan_final<<<nbc, 256, 0, stream>>>(degc, NCn, bsum, off_c, cur_c);
    k_fill<<<2048, 256, 0, stream>>>(dst_v, src_c, edge_attr, off_v, cur_v, col_v, w_v);
    k_fill<<<2048, 256, 0, stream>>>(src_c, dst_v, edge_attr, off_c, cur_c, col_c, w_c);
    k_wsum<<<784, 256, 0, stream>>>(off_v, w_v, wsum_v, NVn);
    k_wsum<<<392, 256, 0, stream>>>(off_c, w_c, wsum_c, NCn);

    // ---- layer 0 (var: 9 feats, cstr: 1 feat) ----
    k_stats_small<9><<<128, 256, 0, stream>>>(var_feats, NVn, accL0v);
    k_stats_small<1><<<128, 256, 0, stream>>>(cstr_feats, NCn, accL0c);
    k_fold<<<1, 64, 0, stream>>>(Wrel_v0, brel_v0, Wroot_v0,
                                 g_c0, b_c0, accL0c, invNC, 1,
                                 g_v0, b_v0, accL0v, invNV, 9,
                                 Wr_v, Wt_v, b0_v, bw_v, (unsigned short*)nullptr);
    k_fold<<<1, 64, 0, stream>>>(Wrel_c0, brel_c0, Wroot_c0,
                                 g_v0, b_v0, accL0v, invNV, 9,
                                 g_c0, b_c0, accL0c, invNC, 1,
                                 Wr_c, Wt_c, b0_c, bw_c, (unsigned short*)nullptr);
    k_agg1<<<784, 256, 0, stream>>>(cstr_feats, off_v, col_v, w_v, V0, NVn);       // [NV,1]
    k_agg<9><<<2048, 256, 0, stream>>>(var_feats, off_c, col_c, w_c, C0, NCn);     // [NC,9]
    k_gemm0<1, 9><<<(NVn * 64 + 255) / 256, 256, 0, stream>>>(V0, var_feats, wsum_v,
                                                              Wr_v, Wt_v, b0_v, bw_v, V1, NVn);
    k_gemm0<9, 1><<<(NCn * 64 + 255) / 256, 256, 0, stream>>>(C0, cstr_feats, wsum_c,
                                                              Wr_c, Wt_c, b0_c, bw_c, C1, NCn);

    // ---- layers 1..3 ----
    float* xv = V1; float* xc = C1; float* av = V0; float* ac = C0;
    for (int l = 0; l < 3; l++) {
        const float* Wrv = Wrel_v + (size_t)l * 4096;
        const float* brv = brel_v + (size_t)l * 64;
        const float* Wtv = Wroot_v + (size_t)l * 4096;
        const float* Wrc = Wrel_c + (size_t)l * 4096;
        const float* brc = brel_c + (size_t)l * 64;
        const float* Wtc = Wroot_c + (size_t)l * 4096;
        const float* gvl = g_v + (size_t)l * 64; const float* bvl = b_v + (size_t)l * 64;
        const float* gcl = g_c + (size_t)l * 64; const float* bcl = b_c + (size_t)l * 64;

        k_stats64<<<1024, 256, 0, stream>>>(xv, NVn, accLv[l]);
        k_stats64<<<1024, 256, 0, stream>>>(xc, NCn, accLc[l]);
        k_fold<<<1, 64, 0, stream>>>(Wrv, brv, Wtv,
                                     gcl, bcl, accLc[l], invNC, 64,
                                     gvl, bvl, accLv[l], invNV, 64,
                                     Wr_v, Wt_v, b0_v, bw_v, Bf_v);
        k_fold<<<1, 64, 0, stream>>>(Wrc, brc, Wtc,
                                     gvl, bvl, accLv[l], invNV, 64,
                                     gcl, bcl, accLc[l], invNC, 64,
                                     Wr_c, Wt_c, b0_c, bw_c, Bf_c);
        k_agg<64><<<2048, 256, 0, stream>>>(xc, off_v, col_v, w_v, av, NVn);
        k_agg<64><<<2048, 256, 0, stream>>>(xv, off_c, col_c, w_c, ac, NCn);
        k_gemm<<<(NVn + 63) / 64, 256, 0, stream>>>(av, xv, wsum_v, Bf_v, b0_v, bw_v, av, NVn);
        k_gemm<<<(NCn + 63) / 64, 256, 0, stream>>>(ac, xc, wsum_c, Bf_c, b0_c, bw_c, ac, NCn);
        // swap
        float* tv = xv; xv = av; av = tv;
        float* tcp = xc; xc = ac; ac = tcp;
    }

    // ---- pooling ----
    k_seg_count<<<(NVn + 255) / 256, 256, 0, stream>>>(var_batch, NVn, cnt_v);
    k_seg_count<<<(NCn + 255) / 256, 256, 0, stream>>>(cstr_batch, NCn, cnt_c);
    k_pool_accum<<<(NVn + 2047) / 2048, 256, 0, stream>>>(xv, var_batch, NVn, pool_sv);
    k_pool_accum<<<(NCn + 2047) / 2048, 256, 0, stream>>>(xc, cstr_batch, NCn, pool_sc);
    k_pool_div<<<(NBb * 128 + 255) / 256, 256, 0, stream>>>(pool_sv, pool_sc, cnt_v, cnt_c, out);
}

// Round 8
// 1304.068 us; speedup vs baseline: 12.2477x; 1.4255x over previous
//
#include <hip/hip_runtime.h>

// Problem constants (match reference setup_inputs)
constexpr int NVn = 200000;   // var nodes, 9 feats in
constexpr int NCn = 100000;   // cstr nodes, 1 feat in
constexpr int NEn = 1000000;  // edges
constexpr int NBb = 32;       // graphs
#define EPSf 1e-5f

typedef __attribute__((ext_vector_type(8))) short s8v;   // 8 bf16 (4 VGPRs)
typedef __attribute__((ext_vector_type(4))) float f4v;   // 4 f32 acc

// f32 -> bf16 bits, round-to-nearest-even
static __device__ __forceinline__ unsigned short f2b(float f) {
    union { float f; unsigned u; } x; x.f = f;
    return (unsigned short)((x.u + 0x7FFFu + ((x.u >> 16) & 1u)) >> 16);
}

// load 8 consecutive f32, convert to bf16x8 fragment
static __device__ __forceinline__ s8v cvt8(const float* p) {
    float4 a = *(const float4*)p;
    float4 b = *(const float4*)(p + 4);
    s8v r;
    r[0] = (short)f2b(a.x); r[1] = (short)f2b(a.y); r[2] = (short)f2b(a.z); r[3] = (short)f2b(a.w);
    r[4] = (short)f2b(b.x); r[5] = (short)f2b(b.y); r[6] = (short)f2b(b.z); r[7] = (short)f2b(b.w);
    return r;
}

// store folded weight W[kg][h] (kg in 0..127, h in 0..63) into MFMA B-fragment order:
// fragment (ks=kg>>5, ct=h>>4), lane = ((kg>>3)&3)<<4 | (h&15), elem j = kg&7
static __device__ __forceinline__ void frag_store(unsigned short* B, int kg, int h, float w) {
    int ks = kg >> 5, g = (kg >> 3) & 3, j = kg & 7, ct = h >> 4;
    int lane = (g << 4) | (h & 15);
    B[((((ks << 2) | ct) << 6) | lane) * 8 + j] = f2b(w);
}

// ---------------- degree count ----------------
__global__ __launch_bounds__(256) void k_count_deg(const int* __restrict__ src, const int* __restrict__ dst,
                            int* __restrict__ degv, int* __restrict__ degc) {
    for (int e = blockIdx.x * blockDim.x + threadIdx.x; e < NEn; e += gridDim.x * blockDim.x) {
        atomicAdd(&degv[dst[e]], 1);
        atomicAdd(&degc[src[e]], 1);
    }
}

// ---------------- exclusive scan (3 kernels, 1024 elems/block) ----------------
__global__ __launch_bounds__(256) void k_scan_block(const int* __restrict__ deg, int n, int* __restrict__ bsum) {
    __shared__ int s[256];
    int base = blockIdx.x * 1024;
    int t = threadIdx.x;
    int v = 0;
#pragma unroll
    for (int j = 0; j < 4; j++) { int idx = base + t * 4 + j; if (idx < n) v += deg[idx]; }
    s[t] = v; __syncthreads();
    for (int o = 128; o > 0; o >>= 1) { if (t < o) s[t] += s[t + o]; __syncthreads(); }
    if (t == 0) bsum[blockIdx.x] = s[0];
}

__global__ __launch_bounds__(1024) void k_scan_tops(int* bsum, int nb) {
    __shared__ int s[1024];
    int t = threadIdx.x;
    int v = (t < nb) ? bsum[t] : 0;
    s[t] = v; __syncthreads();
    for (int o = 1; o < 1024; o <<= 1) {
        int x = (t >= o) ? s[t - o] : 0; __syncthreads();
        s[t] += x; __syncthreads();
    }
    if (t < nb) bsum[t] = s[t] - v;  // exclusive
}

__global__ __launch_bounds__(256) void k_scan_final(const int* __restrict__ deg, int n, const int* __restrict__ bsum,
                             int* __restrict__ off, int* __restrict__ cur) {
    __shared__ int s[256];
    int base = blockIdx.x * 1024, t = threadIdx.x;
    int d[4], loc[4], sum = 0;
#pragma unroll
    for (int j = 0; j < 4; j++) {
        int idx = base + t * 4 + j;
        d[j] = (idx < n) ? deg[idx] : 0;
        loc[j] = sum; sum += d[j];
    }
    s[t] = sum; __syncthreads();
    int v = sum;
    for (int o = 1; o < 256; o <<= 1) {
        int x = (t >= o) ? s[t - o] : 0; __syncthreads();
        s[t] += x; __syncthreads();
    }
    int texcl = s[t] - v + bsum[blockIdx.x];
#pragma unroll
    for (int j = 0; j < 4; j++) {
        int idx = base + t * 4 + j;
        if (idx < n) {
            int o2 = texcl + loc[j];
            off[idx] = o2; cur[idx] = o2;
            if (idx == n - 1) off[n] = o2 + d[j];
        }
    }
}

// ---------------- CSR fill (w = ew / deg) ----------------
__global__ __launch_bounds__(256) void k_fill(const int* __restrict__ key, const int* __restrict__ other,
                       const float* __restrict__ ew, const int* __restrict__ off,
                       int* __restrict__ cur, int* __restrict__ col, float* __restrict__ w) {
    for (int e = blockIdx.x * blockDim.x + threadIdx.x; e < NEn; e += gridDim.x * blockDim.x) {
        int d = key[e];
        int p = atomicAdd(&cur[d], 1);
        col[p] = other[e];
        float invd = 1.0f / (float)(off[d + 1] - off[d]);
        w[p] = ew[e] * invd;
    }
}

__global__ __launch_bounds__(256) void k_wsum(const int* __restrict__ off, const float* __restrict__ w,
                       float* __restrict__ ws, int n) {
    for (int i = blockIdx.x * blockDim.x + threadIdx.x; i < n; i += gridDim.x * blockDim.x) {
        int s = off[i], e = off[i + 1]; float t = 0.f;
        for (int j = s; j < e; j++) t += w[j];
        ws[i] = t;
    }
}

// ---------------- BN column stats ----------------
__global__ __launch_bounds__(256) void k_stats64(const float* __restrict__ x, int n, float* __restrict__ acc) {
    int c = threadIdx.x & 63, r4 = threadIdx.x >> 6;
    float s = 0.f, q = 0.f;
    for (int i = blockIdx.x * 4 + r4; i < n; i += gridDim.x * 4) {
        float v = x[i * 64 + c]; s += v; q = fmaf(v, v, q);
    }
    __shared__ float ls[256];
    ls[threadIdx.x] = s; __syncthreads();
    if (r4 == 0) atomicAdd(&acc[c], ls[c] + ls[c + 64] + ls[c + 128] + ls[c + 192]);
    __syncthreads();
    ls[threadIdx.x] = q; __syncthreads();
    if (r4 == 0) atomicAdd(&acc[64 + c], ls[c] + ls[c + 64] + ls[c + 128] + ls[c + 192]);
}

template <int D>
__global__ __launch_bounds__(256) void k_stats_small(const float* __restrict__ x, int n, float* __restrict__ acc) {
    float s[D], q[D];
#pragma unroll
    for (int k = 0; k < D; k++) { s[k] = 0.f; q[k] = 0.f; }
    for (int i = blockIdx.x * blockDim.x + threadIdx.x; i < n; i += gridDim.x * blockDim.x) {
#pragma unroll
        for (int k = 0; k < D; k++) { float v = x[i * D + k]; s[k] += v; q[k] = fmaf(v, v, q[k]); }
    }
#pragma unroll
    for (int k = 0; k < D; k++) { atomicAdd(&acc[k], s[k]); atomicAdd(&acc[D + k], q[k]); }
}

// ---------------- fold BN into weights (parallel: 256 thr, 4 waves split k-range) ----------
// Round-7 fix: old version was 64 threads x serial-128 loop on one CU (latency-bound,
// launched 8x). Now: phase 1 computes per-k scale a/be in parallel into LDS; phase 2
// splits the k loop across 4 waves; b0/bw LDS-reduced at the end.
__global__ __launch_bounds__(256) void k_fold(const float* __restrict__ Wrel, const float* __restrict__ brel,
                       const float* __restrict__ Wroot,
                       const float* __restrict__ gs, const float* __restrict__ bs,
                       const float* __restrict__ accs, float invNs, int DSv,
                       const float* __restrict__ gd, const float* __restrict__ bd,
                       const float* __restrict__ accd, float invNd, int DDv,
                       float* __restrict__ Wr_o, float* __restrict__ Wt_o,
                       float* __restrict__ b0_o, float* __restrict__ bw_o,
                       unsigned short* __restrict__ Bfrag) {
    __shared__ float sa[128], sbe[128];
    __shared__ float rb0[4][64], rbw[4][64];
    int t = threadIdx.x;
    int total = DSv + DDv;
    for (int k = t; k < total; k += 256) {
        bool isrc = k < DSv;
        int kk = isrc ? k : k - DSv;
        const float* acc = isrc ? accs : accd;
        float invN = isrc ? invNs : invNd;
        int D = isrc ? DSv : DDv;
        float g = isrc ? gs[kk] : gd[kk];
        float b = isrc ? bs[kk] : bd[kk];
        float m = acc[kk] * invN;
        float var = acc[D + kk] * invN - m * m;
        float a = g * rsqrtf(var + EPSf);
        sa[k] = a; sbe[k] = b - m * a;
    }
    __syncthreads();
    int h = t & 63, q = t >> 6;
    float bw = 0.f, b0 = 0.f;
    for (int k = q; k < DSv; k += 4) {
        float wv = Wrel[k * 64 + h];
        float wf = sa[k] * wv;
        Wr_o[k * 64 + h] = wf;
        bw = fmaf(sbe[k], wv, bw);
        if (Bfrag) frag_store(Bfrag, k, h, wf);
    }
    for (int k = q; k < DDv; k += 4) {
        float wv = Wroot[k * 64 + h];
        float wf = sa[DSv + k] * wv;
        Wt_o[k * 64 + h] = wf;
        b0 = fmaf(sbe[DSv + k], wv, b0);
        if (Bfrag) frag_store(Bfrag, 64 + k, h, wf);
    }
    rb0[q][h] = b0; rbw[q][h] = bw;
    __syncthreads();
    if (q == 0) {
        b0_o[h] = brel[h] + rb0[0][h] + rb0[1][h] + rb0[2][h] + rb0[3][h];
        bw_o[h] = rbw[0][h] + rbw[1][h] + rbw[2][h] + rbw[3][h];
    }
}

// ---------------- aggregation (gather form from CSR) ----------------
// wave per node; lane = feature; 4-way unrolled edge loop for memory-level parallelism
template <int DS>
__global__ __launch_bounds__(256) void k_agg(const float* __restrict__ xs, const int* __restrict__ off,
                      const int* __restrict__ col, const float* __restrict__ w,
                      float* __restrict__ agg, int n) {
    int lane = threadIdx.x & 63;
    int wid = (blockIdx.x * blockDim.x + threadIdx.x) >> 6;
    int nw = (gridDim.x * blockDim.x) >> 6;
    for (int i = wid; i < n; i += nw) {
        int s = off[i], e = off[i + 1];
        if (lane < DS) {
            float a0 = 0.f, a1 = 0.f, a2 = 0.f, a3 = 0.f;
            int j = s;
            for (; j + 3 < e; j += 4) {
                int c0 = col[j], c1 = col[j + 1], c2 = col[j + 2], c3 = col[j + 3];
                float w0 = w[j], w1 = w[j + 1], w2 = w[j + 2], w3 = w[j + 3];
                a0 = fmaf(w0, xs[(size_t)c0 * DS + lane], a0);
                a1 = fmaf(w1, xs[(size_t)c1 * DS + lane], a1);
                a2 = fmaf(w2, xs[(size_t)c2 * DS + lane], a2);
                a3 = fmaf(w3, xs[(size_t)c3 * DS + lane], a3);
            }
            for (; j < e; j++) a0 = fmaf(w[j], xs[(size_t)col[j] * DS + lane], a0);
            agg[(size_t)i * DS + lane] = (a0 + a1) + (a2 + a3);
        }
    }
}

// DS==1 specialization: thread per node
__global__ __launch_bounds__(256) void k_agg1(const float* __restrict__ xs, const int* __restrict__ off,
                       const int* __restrict__ col, const float* __restrict__ w,
                       float* __restrict__ agg, int n) {
    for (int i = blockIdx.x * blockDim.x + threadIdx.x; i < n; i += gridDim.x * blockDim.x) {
        int s = off[i], e = off[i + 1]; float a = 0.f;
        for (int j = s; j < e; j++) a = fmaf(w[j], xs[col[j]], a);
        agg[i] = a;
    }
}

// ---------------- layer-0 small-K GEMM: thread per (node, h) ----------------
template <int KS, int KD>
__global__ __launch_bounds__(256) void k_gemm0(const float* __restrict__ aggs, const float* __restrict__ xd,
                        const float* __restrict__ wsum,
                        const float* __restrict__ Wr, const float* __restrict__ Wt,
                        const float* __restrict__ b0, const float* __restrict__ bw,
                        float* __restrict__ out, int n) {
    int idx = blockIdx.x * blockDim.x + threadIdx.x;
    int i = idx >> 6, h = idx & 63;
    if (i >= n) return;
    float acc = b0[h] + wsum[i] * bw[h];
#pragma unroll
    for (int k = 0; k < KS; k++) acc = fmaf(aggs[i * KS + k], Wr[k * 64 + h], acc);
#pragma unroll
    for (int k = 0; k < KD; k++) acc = fmaf(xd[i * KD + k], Wt[k * 64 + h], acc);
    out[i * 64 + h] = fmaxf(acc, 0.0f);
}

// ---------------- main GEMM via MFMA bf16 ----------------
// out[n][64] = relu([agg|x][n][128] @ Bfrag[128][64] + b0 + wsum*bw)
// Block = 256 thr = 4 waves; wave w owns rows [blk*64 + 16w, +16), all 64 cols.
// Per wave: 4 k-steps x 4 col-tiles = 16 x mfma_f32_16x16x32_bf16, acc = 4x f32x4 (AGPR).
// No LDS, no __syncthreads, no per-thread arrays -> cannot spill.
// agg and out alias in-place: each wave reads/writes only its own 16 rows.
__global__ __launch_bounds__(256, 4) void k_gemm(const float* agg, const float* __restrict__ xroot,
                       const float* __restrict__ wsum, const unsigned short* __restrict__ Bfrag,
                       const float* __restrict__ b0, const float* __restrict__ bwv,
                       float* out, int n) {
    int t = threadIdx.x;
    int wv = t >> 6, l = t & 63;
    int lrow = l & 15, lkg = l >> 4;
    int base = blockIdx.x * 64 + wv * 16;
    int arow = base + lrow;
    if (arow >= n) arow = 0;                 // safe redirect for tail block
    const float* ap = agg + (size_t)arow * 64 + lkg * 8;
    const float* xp = xroot + (size_t)arow * 64 + lkg * 8;
    const unsigned short* Bl = Bfrag + l * 8;
    f4v acc0 = {0.f, 0.f, 0.f, 0.f};
    f4v acc1 = acc0, acc2 = acc0, acc3 = acc0;
#define KSTEP(ks, P)                                                        \
    {                                                                       \
        s8v a = cvt8(P);                                                    \
        s8v f0 = *(const s8v*)(Bl + ((ks) * 4 + 0) * 512);                  \
        s8v f1 = *(const s8v*)(Bl + ((ks) * 4 + 1) * 512);                  \
        s8v f2 = *(const s8v*)(Bl + ((ks) * 4 + 2) * 512);                  \
        s8v f3 = *(const s8v*)(Bl + ((ks) * 4 + 3) * 512);                  \
        acc0 = __builtin_amdgcn_mfma_f32_16x16x32_bf16(a, f0, acc0, 0, 0, 0); \
        acc1 = __builtin_amdgcn_mfma_f32_16x16x32_bf16(a, f1, acc1, 0, 0, 0); \
        acc2 = __builtin_amdgcn_mfma_f32_16x16x32_bf16(a, f2, acc2, 0, 0, 0); \
        acc3 = __builtin_amdgcn_mfma_f32_16x16x32_bf16(a, f3, acc3, 0, 0, 0); \
    }
    KSTEP(0, ap)
    KSTEP(1, ap + 32)
    KSTEP(2, xp)
    KSTEP(3, xp + 32)
#undef KSTEP
    // epilogue: C/D layout col = l&15 (+16*ct), row = 4*(l>>4) + reg
    int orow = base + lkg * 4;
    float ws0 = (orow + 0 < n) ? wsum[orow + 0] : 0.f;
    float ws1 = (orow + 1 < n) ? wsum[orow + 1] : 0.f;
    float ws2 = (orow + 2 < n) ? wsum[orow + 2] : 0.f;
    float ws3 = (orow + 3 < n) ? wsum[orow + 3] : 0.f;
#define EPI(ACC, ct)                                                                        \
    {                                                                                       \
        int c = (ct) * 16 + lrow;                                                           \
        float bb = b0[c], wb = bwv[c];                                                      \
        if (orow + 0 < n) out[(size_t)(orow + 0) * 64 + c] = fmaxf(ACC[0] + bb + ws0 * wb, 0.f); \
        if (orow + 1 < n) out[(size_t)(orow + 1) * 64 + c] = fmaxf(ACC[1] + bb + ws1 * wb, 0.f); \
        if (orow + 2 < n) out[(size_t)(orow + 2) * 64 + c] = fmaxf(ACC[2] + bb + ws2 * wb, 0.f); \
        if (orow + 3 < n) out[(size_t)(orow + 3) * 64 + c] = fmaxf(ACC[3] + bb + ws3 * wb, 0.f); \
    }
    EPI(acc0, 0)
    EPI(acc1, 1)
    EPI(acc2, 2)
    EPI(acc3, 3)
#undef EPI
}

// ---------------- pooling ----------------
__global__ __launch_bounds__(256) void k_seg_count(const int* __restrict__ batch, int n, int* __restrict__ cnt) {
    int i = blockIdx.x * blockDim.x + threadIdx.x;
    if (i >= n) return;
    int lane = threadIdx.x & 63;
    int b = batch[i];
    int bprev = __shfl_up(b, 1);
    bool head = (lane == 0) || (b != bprev);
    unsigned long long hb = __ballot(head);
    if (head) {
        unsigned long long mask = (lane == 63) ? 0ULL : (hb >> (lane + 1));
        int wstart = i - lane;
        int nvalid = min(64, n - wstart);
        int end = (mask == 0ULL) ? nvalid : (lane + 1 + __ffsll((long long)mask) - 1);
        atomicAdd(&cnt[b], end - lane);
    }
}

// Round-7 fix: was 98 blocks x 512 serial rows/thread -> 155 GB/s (occupancy-starved).
// Now 128 rows/block (32/walker), grid ~1563: BW-bound. batch sorted -> ~1 run/walker
// -> ~400K atomics over 2048 addresses, negligible contention.
__global__ __launch_bounds__(256) void k_pool_accum(const float* __restrict__ x, const int* __restrict__ batch,
                             int n, float* __restrict__ sums) {
    int c = threadIdx.x & 63, r4 = threadIdx.x >> 6;
    int base = blockIdx.x * 128 + r4 * 32;
    int end = min(n, base + 32);
    float acc = 0.f; int cur = -1;
    for (int i = base; i < end; ++i) {
        int b = batch[i];
        if (b != cur) {
            if (cur >= 0) atomicAdd(&sums[cur * 64 + c], acc);
            acc = 0.f; cur = b;
        }
        acc += x[(size_t)i * 64 + c];
    }
    if (cur >= 0) atomicAdd(&sums[cur * 64 + c], acc);
}

__global__ __launch_bounds__(256) void k_pool_div(const float* __restrict__ sv, const float* __restrict__ sc,
                           const int* __restrict__ cv, const int* __restrict__ cc2,
                           float* __restrict__ out) {
    int idx = blockIdx.x * blockDim.x + threadIdx.x;
    if (idx >= NBb * 128) return;
    int b = idx >> 7, j = idx & 127;
    float v;
    if (j < 64) v = sv[b * 64 + j] / fmaxf((float)cv[b], 1.0f);
    else        v = sc[b * 64 + (j - 64)] / fmaxf((float)cc2[b], 1.0f);
    out[idx] = v;
}

// ==================================================================
extern "C" void kernel_launch(void* const* d_in, const int* in_sizes, int n_in,
                              void* d_out, int out_size, void* d_ws, size_t ws_size,
                              hipStream_t stream) {
    (void)in_sizes; (void)n_in; (void)out_size; (void)ws_size;
    const float* var_feats = (const float*)d_in[0];
    const float* cstr_feats = (const float*)d_in[1];
    const float* edge_attr = (const float*)d_in[2];
    const float* Wrel_v0 = (const float*)d_in[3];
    const float* brel_v0 = (const float*)d_in[4];
    const float* Wroot_v0 = (const float*)d_in[5];
    const float* Wrel_c0 = (const float*)d_in[6];
    const float* brel_c0 = (const float*)d_in[7];
    const float* Wroot_c0 = (const float*)d_in[8];
    const float* g_v0 = (const float*)d_in[9];
    const float* b_v0 = (const float*)d_in[10];
    const float* g_c0 = (const float*)d_in[11];
    const float* b_c0 = (const float*)d_in[12];
    const float* Wrel_v = (const float*)d_in[13];
    const float* brel_v = (const float*)d_in[14];
    const float* Wroot_v = (const float*)d_in[15];
    const float* Wrel_c = (const float*)d_in[16];
    const float* brel_c = (const float*)d_in[17];
    const float* Wroot_c = (const float*)d_in[18];
    const float* g_v = (const float*)d_in[19];
    const float* b_v = (const float*)d_in[20];
    const float* g_c = (const float*)d_in[21];
    const float* b_c = (const float*)d_in[22];
    const int* edge_index = (const int*)d_in[23];
    const int* var_batch = (const int*)d_in[24];
    const int* cstr_batch = (const int*)d_in[25];
    const int* src_c = edge_index;
    const int* dst_v = edge_index + NEn;
    float* out = (float*)d_out;

    // ---- workspace carve-out ----
    char* ws = (char*)d_ws;
    size_t off_b = 0;
    auto alloc = [&](size_t bytes) -> char* {
        char* p = ws + off_b;
        off_b = (off_b + bytes + 255) & ~(size_t)255;
        return p;
    };
    float* V0 = (float*)alloc((size_t)NVn * 64 * 4);
    float* V1 = (float*)alloc((size_t)NVn * 64 * 4);
    float* C0 = (float*)alloc((size_t)NCn * 64 * 4);
    float* C1 = (float*)alloc((size_t)NCn * 64 * 4);
    int* off_v = (int*)alloc((size_t)(NVn + 1) * 4);
    int* cur_v = (int*)alloc((size_t)NVn * 4);
    int* col_v = (int*)alloc((size_t)NEn * 4);
    float* w_v = (float*)alloc((size_t)NEn * 4);
    int* off_c = (int*)alloc((size_t)(NCn + 1) * 4);
    int* cur_c = (int*)alloc((size_t)NCn * 4);
    int* col_c = (int*)alloc((size_t)NEn * 4);
    float* w_c = (float*)alloc((size_t)NEn * 4);
    float* wsum_v = (float*)alloc((size_t)NVn * 4);
    float* wsum_c = (float*)alloc((size_t)NCn * 4);
    int* degzone = (int*)alloc((size_t)(NVn + NCn) * 4);
    int* degv = degzone;
    int* degc = degzone + NVn;
    int* bsum = (int*)alloc(1024 * 4);
    // zero-init zone (one memset): stats accums + pool sums + counts
    float* zzone = (float*)alloc(4992 * 4);
    float* accL0v = zzone;            // 32 (18 used)
    float* accL0c = zzone + 32;       // 8 (2 used)
    float* accLv[3], *accLc[3];
    for (int l = 0; l < 3; l++) { accLv[l] = zzone + 64 + l * 256; accLc[l] = zzone + 64 + l * 256 + 128; }
    float* pool_sv = zzone + 832;     // 2048
    float* pool_sc = zzone + 2880;    // 2048
    int* cnt_v = (int*)(zzone + 4928);  // 32
    int* cnt_c = (int*)(zzone + 4960);  // 32
    // folded weights
    float* Wr_v = (float*)alloc(4096 * 4);
    float* Wt_v = (float*)alloc(4096 * 4);
    float* b0_v = (float*)alloc(64 * 4);
    float* bw_v = (float*)alloc(64 * 4);
    float* Wr_c = (float*)alloc(4096 * 4);
    float* Wt_c = (float*)alloc(4096 * 4);
    float* b0_c = (float*)alloc(64 * 4);
    float* bw_c = (float*)alloc(64 * 4);
    // bf16 MFMA B-fragment buffers: [ks4][ct4][lane64][8 bf16]
    unsigned short* Bf_v = (unsigned short*)alloc(8192 * 2);
    unsigned short* Bf_c = (unsigned short*)alloc(8192 * 2);

    const float invNV = 1.0f / (float)NVn;
    const float invNC = 1.0f / (float)NCn;

    // ---- init ----
    hipMemsetAsync(degzone, 0, (size_t)(NVn + NCn) * 4, stream);
    hipMemsetAsync(zzone, 0, 4992 * 4, stream);

    // ---- build CSR both directions ----
    k_count_deg<<<2048, 256, 0, stream>>>(src_c, dst_v, degv, degc);
    int nbv = (NVn + 1023) / 1024;  // 196
    int nbc = (NCn + 1023) / 1024;  // 98
    k_scan_block<<<nbv, 256, 0, stream>>>(degv, NVn, bsum);
    k_scan_tops<<<1, 1024, 0, stream>>>(bsum, nbv);
    k_scan_final<<<nbv, 256, 0, stream>>>(degv, NVn, bsum, off_v, cur_v);
    k_scan_block<<<nbc, 256, 0, stream>>>(degc, NCn, bsum);
    k_scan_tops<<<1, 1024, 0, stream>>>(bsum, nbc);
    k_scan_final<<<nbc, 256, 0, stream>>>(degc, NCn, bsum, off_c, cur_c);
    k_fill<<<2048, 256, 0, stream>>>(dst_v, src_c, edge_attr, off_v, cur_v, col_v, w_v);
    k_fill<<<2048, 256, 0, stream>>>(src_c, dst_v, edge_attr, off_c, cur_c, col_c, w_c);
    k_wsum<<<784, 256, 0, stream>>>(off_v, w_v, wsum_v, NVn);
    k_wsum<<<392, 256, 0, stream>>>(off_c, w_c, wsum_c, NCn);

    // ---- layer 0 (var: 9 feats, cstr: 1 feat) ----
    k_stats_small<9><<<128, 256, 0, stream>>>(var_feats, NVn, accL0v);
    k_stats_small<1><<<128, 256, 0, stream>>>(cstr_feats, NCn, accL0c);
    k_fold<<<1, 256, 0, stream>>>(Wrel_v0, brel_v0, Wroot_v0,
                                 g_c0, b_c0, accL0c, invNC, 1,
                                 g_v0, b_v0, accL0v, invNV, 9,
                                 Wr_v, Wt_v, b0_v, bw_v, (unsigned short*)nullptr);
    k_fold<<<1, 256, 0, stream>>>(Wrel_c0, brel_c0, Wroot_c0,
                                 g_v0, b_v0, accL0v, invNV, 9,
                                 g_c0, b_c0, accL0c, invNC, 1,
                                 Wr_c, Wt_c, b0_c, bw_c, (unsigned short*)nullptr);
    k_agg1<<<784, 256, 0, stream>>>(cstr_feats, off_v, col_v, w_v, V0, NVn);       // [NV,1]
    k_agg<9><<<2048, 256, 0, stream>>>(var_feats, off_c, col_c, w_c, C0, NCn);     // [NC,9]
    k_gemm0<1, 9><<<(NVn * 64 + 255) / 256, 256, 0, stream>>>(V0, var_feats, wsum_v,
                                                              Wr_v, Wt_v, b0_v, bw_v, V1, NVn);
    k_gemm0<9, 1><<<(NCn * 64 + 255) / 256, 256, 0, stream>>>(C0, cstr_feats, wsum_c,
                                                              Wr_c, Wt_c, b0_c, bw_c, C1, NCn);

    // ---- layers 1..3 ----
    float* xv = V1; float* xc = C1; float* av = V0; float* ac = C0;
    for (int l = 0; l < 3; l++) {
        const float* Wrv = Wrel_v + (size_t)l * 4096;
        const float* brv = brel_v + (size_t)l * 64;
        const float* Wtv = Wroot_v + (size_t)l * 4096;
        const float* Wrc = Wrel_c + (size_t)l * 4096;
        const float* brc = brel_c + (size_t)l * 64;
        const float* Wtc = Wroot_c + (size_t)l * 4096;
        const float* gvl = g_v + (size_t)l * 64; const float* bvl = b_v + (size_t)l * 64;
        const float* gcl = g_c + (size_t)l * 64; const float* bcl = b_c + (size_t)l * 64;

        k_stats64<<<1024, 256, 0, stream>>>(xv, NVn, accLv[l]);
        k_stats64<<<1024, 256, 0, stream>>>(xc, NCn, accLc[l]);
        k_fold<<<1, 256, 0, stream>>>(Wrv, brv, Wtv,
                                     gcl, bcl, accLc[l], invNC, 64,
                                     gvl, bvl, accLv[l], invNV, 64,
                                     Wr_v, Wt_v, b0_v, bw_v, Bf_v);
        k_fold<<<1, 256, 0, stream>>>(Wrc, brc, Wtc,
                                     gvl, bvl, accLv[l], invNV, 64,
                                     gcl, bcl, accLc[l], invNC, 64,
                                     Wr_c, Wt_c, b0_c, bw_c, Bf_c);
        k_agg<64><<<2048, 256, 0, stream>>>(xc, off_v, col_v, w_v, av, NVn);
        k_agg<64><<<2048, 256, 0, stream>>>(xv, off_c, col_c, w_c, ac, NCn);
        k_gemm<<<(NVn + 63) / 64, 256, 0, stream>>>(av, xv, wsum_v, Bf_v, b0_v, bw_v, av, NVn);
        k_gemm<<<(NCn + 63) / 64, 256, 0, stream>>>(ac, xc, wsum_c, Bf_c, b0_c, bw_c, ac, NCn);
        // swap
        float* tv = xv; xv = av; av = tv;
        float* tcp = xc; xc = ac; ac = tcp;
    }

    // ---- pooling ----
    k_seg_count<<<(NVn + 255) / 256, 256, 0, stream>>>(var_batch, NVn, cnt_v);
    k_seg_count<<<(NCn + 255) / 256, 256, 0, stream>>>(cstr_batch, NCn, cnt_c);
    k_pool_accum<<<(NVn + 127) / 128, 256, 0, stream>>>(xv, var_batch, NVn, pool_sv);
    k_pool_accum<<<(NCn + 127) / 128, 256, 0, stream>>>(xc, cstr_batch, NCn, pool_sc);
    k_pool_div<<<(NBb * 128 + 255) / 256, 256, 0, stream>>>(pool_sv, pool_sc, cnt_v, cnt_c, out);
}